// Round 8
// baseline (429.412 us; speedup 1.0000x reference)
//
#include <hip/hip_runtime.h>
#include <hip/hip_bf16.h>
#include <math.h>

#define H 128
#define NB 8
#define NVN 1024   // virtual nodes per batch
#define MLIG 64    // ligand atoms per batch
#define J 64       // H/2

// Measurement round 2: amplify the three AUX kernels x32 (idempotent) to
// surface each in rocprof top-5 and split R6's unexplained 43 us into
// {combine, project, softmax, gaps}. pair_mlp runs x1 (with one barrier
// per chunk instead of two).
#define AUX_REPEAT 32

typedef _Float16 f16;
typedef __attribute__((ext_vector_type(8))) _Float16 f16x8;
typedef __attribute__((ext_vector_type(4))) _Float16 f16x4;
typedef __attribute__((ext_vector_type(4))) float f32x4;

__device__ __forceinline__ f16x8 relu8(f16x8 x) {
    f16x8 z;
    #pragma unroll
    for (int i = 0; i < 8; ++i) z[i] = x[i] > (_Float16)0 ? x[i] : (_Float16)0;
    return z;
}

template <int CTRL>
__device__ __forceinline__ float dpp_add(float x) {
    union { float f; int i; } u, r;
    u.f = x;
    r.i = __builtin_amdgcn_update_dpp(0, u.i, CTRL, 0xf, 0xf, true);
    return x + r.f;
}
__device__ __forceinline__ float row16_sum(float x) {
    x = dpp_add<0xB1>(x);
    x = dpp_add<0x4E>(x);
    x = dpp_add<0x141>(x);
    x = dpp_add<0x140>(x);
    return x;
}

// -------------------------------------------------------------------------
// Kernel 1: fold the two projection layers into combined weights. (x32)
// -------------------------------------------------------------------------
__global__ __launch_bounds__(256) void combine_weights2(
    const float* __restrict__ Wv, const float* __restrict__ bv,
    const float* __restrict__ Wl, const float* __restrict__ bl,
    const float* __restrict__ W1, const float* __restrict__ b1,
    float* __restrict__ Wc_v, float* __restrict__ Wc_l,
    float* __restrict__ bias_v, float* __restrict__ bias_l)
{
    __shared__ float part[256];
    __shared__ float partb[256];
    const int tid = threadIdx.x;
    const int o   = tid & 127;
    const int kh  = tid >> 7;
    const int d   = blockIdx.x;
    const int mat = blockIdx.y;

    const float* Wsrc = (mat == 0) ? Wv : Wl;
    const float* W1p  = (mat == 0) ? (W1 + H * H) : W1;
    const float* bsrc = (mat == 0) ? bv : bl;
    float* dst        = (mat == 0) ? Wc_v : Wc_l;

    #pragma unroll 1
    for (int rep = 0; rep < AUX_REPEAT; ++rep) {
        float acc = 0.f, accb = 0.f;
        #pragma unroll 8
        for (int k = kh * 64; k < kh * 64 + 64; ++k) {
            float w = W1p[k * H + o];
            acc  += Wsrc[d * H + k] * w;
            accb += bsrc[k] * w;
        }
        part[tid]  = acc;
        partb[tid] = accb;
        __syncthreads();

        if (kh == 0) {
            dst[d * H + o] = part[o] + part[o + 128];
            if (d == 0) {
                float bb = partb[o] + partb[o + 128];
                if (mat == 0) bias_v[o] = bb;
                else          bias_l[o] = bb + b1[o];
            }
        }
        __syncthreads();
    }
}

// -------------------------------------------------------------------------
// Kernel 2: projections as register-tiled fp32 GEMM, f16 output. (x32)
// -------------------------------------------------------------------------
__global__ __launch_bounds__(256) void project2(
    const float* __restrict__ VE, const float* __restrict__ LE,
    const float* __restrict__ Wc_v, const float* __restrict__ Wc_l,
    const float* __restrict__ bias_v, const float* __restrict__ bias_l,
    f16* __restrict__ v_h, f16* __restrict__ l_h)
{
    __shared__ float Xs[32][132];
    const int bid = blockIdx.x;
    const int tid = threadIdx.x;

    const float* src; const float* Wc; const float* bias; f16* dst; int r0;
    if (bid < 256) { src = VE; Wc = Wc_v; bias = bias_v; dst = v_h; r0 = bid * 32; }
    else           { src = LE; Wc = Wc_l; bias = bias_l; dst = l_h; r0 = (bid - 256) * 32; }

    #pragma unroll 1
    for (int rep = 0; rep < AUX_REPEAT; ++rep) {
        #pragma unroll
        for (int i = 0; i < 4; ++i) {
            int idx = tid + i * 256;
            int r = idx >> 5, cg = idx & 31;
            *(f32x4*)&Xs[r][cg * 4] = *(const f32x4*)&src[(size_t)(r0 + r) * H + cg * 4];
        }
        __syncthreads();

        const int rt = (tid >> 5) * 4;
        const int c0 = (tid & 31) * 4;

        f32x4 bb = *(const f32x4*)&bias[c0];
        f32x4 acc[4];
        #pragma unroll
        for (int i = 0; i < 4; ++i) acc[i] = bb;

        #pragma unroll 4
        for (int k4 = 0; k4 < 32; ++k4) {
            f32x4 xr[4];
            #pragma unroll
            for (int i = 0; i < 4; ++i) xr[i] = *(const f32x4*)&Xs[rt + i][k4 * 4];
            f32x4 w0 = *(const f32x4*)&Wc[(size_t)(k4 * 4 + 0) * H + c0];
            f32x4 w1 = *(const f32x4*)&Wc[(size_t)(k4 * 4 + 1) * H + c0];
            f32x4 w2 = *(const f32x4*)&Wc[(size_t)(k4 * 4 + 2) * H + c0];
            f32x4 w3 = *(const f32x4*)&Wc[(size_t)(k4 * 4 + 3) * H + c0];
            #pragma unroll
            for (int i = 0; i < 4; ++i) {
                acc[i] += xr[i][0] * w0;
                acc[i] += xr[i][1] * w1;
                acc[i] += xr[i][2] * w2;
                acc[i] += xr[i][3] * w3;
            }
        }

        #pragma unroll
        for (int i = 0; i < 4; ++i) {
            f16x4 hv;
            hv[0] = (f16)acc[i][0]; hv[1] = (f16)acc[i][1];
            hv[2] = (f16)acc[i][2]; hv[3] = (f16)acc[i][3];
            *(f16x4*)&dst[(size_t)(r0 + rt + i) * H + c0] = hv;
        }
        __syncthreads();
    }
}

// -------------------------------------------------------------------------
// Kernel 3: pairwise MLP -> z. Same as R6 but ONE barrier per chunk
// (double buffering makes the end-of-chunk barrier redundant: a wave
// passes barrier(ch+1) only after all waves finished compute(ch), so
// write(ch+2) into buf[ch&1] cannot race compute(ch)'s reads).
// -------------------------------------------------------------------------
__global__ __launch_bounds__(512) void pair_mlp(
    const f16* __restrict__ v_h, const f16* __restrict__ l_h,
    const float* __restrict__ W2, const float* __restrict__ b2,
    const float* __restrict__ W3, float* __restrict__ zbuf)
{
    __shared__ f16 Xs[2][64 * 128];    // 32 KB

    const int bid = blockIdx.x;
    const int wg  = (bid & 7) * 64 + (bid >> 3);
    const int half = wg & 1;
    const int pair = wg >> 1;
    const int bm0  = pair * 2;
    const int b    = bm0 >> 6;

    const int tid  = threadIdx.x;
    const int w    = tid >> 6;
    const int mi   = w >> 2;
    const int wl   = w & 3;
    const int lane = tid & 63;
    const int g    = lane >> 4;
    const int c    = lane & 15;
    const int bm   = bm0 + mi;

    f16x8 bw[4][4];
    #pragma unroll
    for (int ks = 0; ks < 4; ++ks)
        #pragma unroll
        for (int fj = 0; fj < 4; ++fj) {
            f16x8 f;
            #pragma unroll
            for (int e = 0; e < 8; ++e)
                f[e] = (f16)W2[(ks * 32 + g * 8 + e) * J + fj * 16 + c];
            bw[ks][fj] = f;
        }

    f16x8 lp[4];
    #pragma unroll
    for (int ks = 0; ks < 4; ++ks)
        lp[ks] = *(const f16x8*)&l_h[(size_t)bm * H + ks * 32 + g * 8];

    float b2r[4], w3r[4];
    #pragma unroll
    for (int fj = 0; fj < 4; ++fj) {
        b2r[fj] = b2[fj * 16 + c];
        w3r[fj] = W3[fj * 16 + c];
    }

    const f16* vsrc = v_h + ((size_t)b * NVN + half * 512) * H;

    const int wrow = tid >> 4;
    const int wchk = (tid & 15) ^ (wrow & 7);
    const int wr0  = wrow * 128 + wchk * 8;
    const int wr1  = wr0 + 32 * 128;
    const int rrow = (wl * 16 + c) * 128;
    const int rx   = c & 7;

    float* zdst = zbuf + (size_t)bm0 * NVN + half * 512;

    f16x8 st0 = *(const f16x8*)&vsrc[(size_t)tid * 8];
    f16x8 st1 = *(const f16x8*)&vsrc[(size_t)(tid + 512) * 8];

    #pragma unroll 1
    for (int ch = 0; ch < 8; ++ch) {
        f16* buf = Xs[ch & 1];
        *(f16x8*)&buf[wr0] = st0;
        *(f16x8*)&buf[wr1] = st1;
        __syncthreads();

        if (ch < 7) {
            const f16* p = vsrc + (size_t)(ch + 1) * 64 * H;
            st0 = *(const f16x8*)&p[(size_t)tid * 8];
            st1 = *(const f16x8*)&p[(size_t)(tid + 512) * 8];
        }

        f32x4 acc[4];
        #pragma unroll
        for (int fj = 0; fj < 4; ++fj) acc[fj] = (f32x4){0.f, 0.f, 0.f, 0.f};

        #pragma unroll
        for (int ks = 0; ks < 4; ++ks) {
            f16x8 xv = *(const f16x8*)&buf[rrow + (((ks * 4 + g) ^ rx) * 8)];
            f16x8 af = relu8(xv + lp[ks]);
            #pragma unroll
            for (int fj = 0; fj < 4; ++fj)
                acc[fj] = __builtin_amdgcn_mfma_f32_16x16x32_f16(
                    af, bw[ks][fj], acc[fj], 0, 0, 0);
        }

        float pz[4];
        #pragma unroll
        for (int r = 0; r < 4; ++r) {
            float s = fmaxf(acc[0][r] + b2r[0], 0.f) * w3r[0]
                    + fmaxf(acc[1][r] + b2r[1], 0.f) * w3r[1]
                    + fmaxf(acc[2][r] + b2r[2], 0.f) * w3r[2]
                    + fmaxf(acc[3][r] + b2r[3], 0.f) * w3r[3];
            pz[r] = row16_sum(s);
        }
        if (c < 4) {
            float zv = (c == 0) ? pz[0] : (c == 1) ? pz[1] : (c == 2) ? pz[2] : pz[3];
            zdst[(size_t)mi * NVN + ch * 64 + wl * 16 + g * 4 + c] = zv;
        }
        // no end-of-chunk barrier: double buffer + next iteration's barrier
        // already order write(ch+2) after all compute(ch) reads.
    }
}

// -------------------------------------------------------------------------
// Kernel 4: per-(b,m) softmax over z + attn write + coords einsum. (x32)
// -------------------------------------------------------------------------
__global__ __launch_bounds__(256) void softmax_coords(
    const float* __restrict__ zbuf, const float* __restrict__ vc,
    float* __restrict__ out_coords, float* __restrict__ out_attn)
{
    __shared__ float red[4];
    __shared__ float redc[3][4];

    const int tid = threadIdx.x;
    const int bm  = blockIdx.x;
    const int b   = bm >> 6;
    const int wid = tid >> 6, lane = tid & 63;

    #pragma unroll 1
    for (int rep = 0; rep < AUX_REPEAT; ++rep) {
        float zloc[4];
        float mx = -INFINITY;
        #pragma unroll
        for (int k = 0; k < 4; ++k) {
            zloc[k] = zbuf[(size_t)bm * NVN + tid + k * 256];
            mx = fmaxf(mx, zloc[k]);
        }
        #pragma unroll
        for (int off = 32; off > 0; off >>= 1) mx = fmaxf(mx, __shfl_xor(mx, off));
        if (lane == 0) red[wid] = mx;
        __syncthreads();
        if (tid == 0)
            red[0] = fmaxf(fmaxf(red[0], red[1]), fmaxf(red[2], red[3]));
        __syncthreads();
        const float gmax = red[0];
        __syncthreads();

        float s = 0.f;
        #pragma unroll
        for (int k = 0; k < 4; ++k) {
            zloc[k] = expf(zloc[k] - gmax);
            s += zloc[k];
        }
        #pragma unroll
        for (int off = 32; off > 0; off >>= 1) s += __shfl_xor(s, off);
        if (lane == 0) red[wid] = s;
        __syncthreads();
        if (tid == 0) red[0] = red[0] + red[1] + red[2] + red[3];
        __syncthreads();
        const float inv = 1.f / red[0];

        float cx = 0.f, cy = 0.f, cz = 0.f;
        #pragma unroll
        for (int k = 0; k < 4; ++k) {
            int n = tid + k * 256;
            float a = zloc[k] * inv;
            out_attn[(size_t)bm * NVN + n] = a;
            const float* vcp = vc + (size_t)(b * NVN + n) * 3;
            cx += a * vcp[0];
            cy += a * vcp[1];
            cz += a * vcp[2];
        }
        #pragma unroll
        for (int off = 32; off > 0; off >>= 1) {
            cx += __shfl_xor(cx, off);
            cy += __shfl_xor(cy, off);
            cz += __shfl_xor(cz, off);
        }
        if (lane == 0) { redc[0][wid] = cx; redc[1][wid] = cy; redc[2][wid] = cz; }
        __syncthreads();
        if (tid == 0) {
            out_coords[bm * 3 + 0] = redc[0][0] + redc[0][1] + redc[0][2] + redc[0][3];
            out_coords[bm * 3 + 1] = redc[1][0] + redc[1][1] + redc[1][2] + redc[1][3];
            out_coords[bm * 3 + 2] = redc[2][0] + redc[2][1] + redc[2][2] + redc[2][3];
        }
        __syncthreads();
    }
}

// -------------------------------------------------------------------------
extern "C" void kernel_launch(void* const* d_in, const int* in_sizes, int n_in,
                              void* d_out, int out_size, void* d_ws, size_t ws_size,
                              hipStream_t stream)
{
    const float* VE = (const float*)d_in[0];   // [8192, 128]
    const float* vc = (const float*)d_in[1];   // [8192, 3]
    const float* LE = (const float*)d_in[2];   // [512, 128]
    const float* Wv = (const float*)d_in[6];
    const float* bv = (const float*)d_in[7];
    const float* Wl = (const float*)d_in[8];
    const float* bl = (const float*)d_in[9];
    const float* W1 = (const float*)d_in[10];
    const float* b1 = (const float*)d_in[11];
    const float* W2 = (const float*)d_in[12];
    const float* b2 = (const float*)d_in[13];
    const float* W3 = (const float*)d_in[14];
    // b3 cancels in softmax

    float* ws     = (float*)d_ws;
    float* Wc_v   = ws;
    float* Wc_l   = ws + 16384;
    float* bias_v = ws + 32768;
    float* bias_l = ws + 32896;
    f16*   v_hp   = (f16*)(ws + 33024);
    f16*   l_hp   = v_hp + (size_t)NB * NVN * H;
    float* zbuf   = ws + 33024 + ((size_t)NB * NVN * H + 512 * H) / 2;

    float* out_coords = (float*)d_out;
    float* out_attn   = out_coords + NB * MLIG * 3;

    combine_weights2<<<dim3(H, 2), 256, 0, stream>>>(
        Wv, bv, Wl, bl, W1, b1, Wc_v, Wc_l, bias_v, bias_l);

    project2<<<256 + 16, 256, 0, stream>>>(
        VE, LE, Wc_v, Wc_l, bias_v, bias_l, v_hp, l_hp);

    pair_mlp<<<512, 512, 0, stream>>>(
        v_hp, l_hp, W2, b2, W3, zbuf);

    softmax_coords<<<NB * MLIG, 256, 0, stream>>>(
        zbuf, vc, out_coords, out_attn);
}

// Round 9
// 53.848 us; speedup vs baseline: 7.9746x; 7.9746x over previous
//
#include <hip/hip_runtime.h>
#include <hip/hip_bf16.h>
#include <math.h>

#define H 128
#define NB 8
#define NVN 1024   // virtual nodes per batch
#define MLIG 64    // ligand atoms per batch
#define J 64       // H/2

typedef _Float16 f16;
typedef __attribute__((ext_vector_type(8))) _Float16 f16x8;
typedef __attribute__((ext_vector_type(4))) _Float16 f16x4;
typedef __attribute__((ext_vector_type(4))) float f32x4;

__device__ __forceinline__ f16x8 relu8(f16x8 x) {
    f16x8 z;
    #pragma unroll
    for (int i = 0; i < 8; ++i) z[i] = x[i] > (_Float16)0 ? x[i] : (_Float16)0;
    return z;
}

template <int CTRL>
__device__ __forceinline__ float dpp_add(float x) {
    union { float f; int i; } u, r;
    u.f = x;
    r.i = __builtin_amdgcn_update_dpp(0, u.i, CTRL, 0xf, 0xf, true);
    return x + r.f;
}
__device__ __forceinline__ float row16_sum(float x) {
    x = dpp_add<0xB1>(x);   // xor 1
    x = dpp_add<0x4E>(x);   // xor 2
    x = dpp_add<0x141>(x);  // xor 4 (row_half_mirror)
    x = dpp_add<0x140>(x);  // xor 8 (row_mirror)
    return x;
}

// -------------------------------------------------------------------------
// Kernel 1: direct projection, NO combine kernel. v_part = (VE@Wv+bv)@W1v,
// l_part = (LE@Wl+bl)@W1l + b1 — linear, so two chained per-tile GEMMs give
// the identical result in fp32. 16-row tiles, grid 544 (2.1 blocks/CU for
// latency hiding of the L2-resident weight loads). f16 output.
// -------------------------------------------------------------------------
__global__ __launch_bounds__(256) void project_direct(
    const float* __restrict__ VE, const float* __restrict__ LE,
    const float* __restrict__ Wv, const float* __restrict__ bv,
    const float* __restrict__ Wl, const float* __restrict__ bl,
    const float* __restrict__ W1, const float* __restrict__ b1,
    f16* __restrict__ v_h, f16* __restrict__ l_h)
{
    __shared__ float Xs[16][132];
    __shared__ float Ts[16][132];
    const int bid = blockIdx.x;
    const int tid = threadIdx.x;

    const float* src; const float* Wa; const float* ba; const float* Wb;
    f16* dst; int r0; bool lig;
    if (bid < 512) { src = VE; Wa = Wv; ba = bv; Wb = W1 + H * H;
                     dst = v_h; r0 = bid * 16; lig = false; }
    else           { src = LE; Wa = Wl; ba = bl; Wb = W1;
                     dst = l_h; r0 = (bid - 512) * 16; lig = true; }

    // stage X tile (16 x 128 fp32), coalesced
    #pragma unroll
    for (int i = 0; i < 2; ++i) {
        int s = tid + i * 256;
        int r = s >> 5, c4 = (s & 31) * 4;
        *(f32x4*)&Xs[r][c4] = *(const f32x4*)&src[(size_t)(r0 + r) * H + c4];
    }
    __syncthreads();

    const int rt = (tid >> 5) * 2;     // 2 rows
    const int c0 = (tid & 31) * 4;     // 4 cols

    // ---- stage 1: tmp = X @ Wa + ba
    f32x4 a0 = *(const f32x4*)&ba[c0];
    f32x4 a1 = a0;
    #pragma unroll 4
    for (int k4 = 0; k4 < 32; ++k4) {
        f32x4 x0 = *(const f32x4*)&Xs[rt][k4 * 4];
        f32x4 x1 = *(const f32x4*)&Xs[rt + 1][k4 * 4];
        f32x4 w0 = *(const f32x4*)&Wa[(size_t)(k4 * 4 + 0) * H + c0];
        f32x4 w1 = *(const f32x4*)&Wa[(size_t)(k4 * 4 + 1) * H + c0];
        f32x4 w2 = *(const f32x4*)&Wa[(size_t)(k4 * 4 + 2) * H + c0];
        f32x4 w3 = *(const f32x4*)&Wa[(size_t)(k4 * 4 + 3) * H + c0];
        a0 += x0[0] * w0; a0 += x0[1] * w1; a0 += x0[2] * w2; a0 += x0[3] * w3;
        a1 += x1[0] * w0; a1 += x1[1] * w1; a1 += x1[2] * w2; a1 += x1[3] * w3;
    }
    *(f32x4*)&Ts[rt][c0]     = a0;
    *(f32x4*)&Ts[rt + 1][c0] = a1;
    __syncthreads();

    // ---- stage 2: out = tmp @ Wb (+ b1 for ligand)
    f32x4 b0;
    if (lig) b0 = *(const f32x4*)&b1[c0];
    else     b0 = (f32x4){0.f, 0.f, 0.f, 0.f};
    f32x4 b1a = b0;
    #pragma unroll 4
    for (int k4 = 0; k4 < 32; ++k4) {
        f32x4 x0 = *(const f32x4*)&Ts[rt][k4 * 4];
        f32x4 x1 = *(const f32x4*)&Ts[rt + 1][k4 * 4];
        f32x4 w0 = *(const f32x4*)&Wb[(size_t)(k4 * 4 + 0) * H + c0];
        f32x4 w1 = *(const f32x4*)&Wb[(size_t)(k4 * 4 + 1) * H + c0];
        f32x4 w2 = *(const f32x4*)&Wb[(size_t)(k4 * 4 + 2) * H + c0];
        f32x4 w3 = *(const f32x4*)&Wb[(size_t)(k4 * 4 + 3) * H + c0];
        b0  += x0[0] * w0; b0  += x0[1] * w1; b0  += x0[2] * w2; b0  += x0[3] * w3;
        b1a += x1[0] * w0; b1a += x1[1] * w1; b1a += x1[2] * w2; b1a += x1[3] * w3;
    }

    f16x4 h0, h1;
    #pragma unroll
    for (int i = 0; i < 4; ++i) { h0[i] = (f16)b0[i]; h1[i] = (f16)b1a[i]; }
    *(f16x4*)&dst[(size_t)(r0 + rt) * H + c0]     = h0;
    *(f16x4*)&dst[(size_t)(r0 + rt + 1) * H + c0] = h1;
}

// -------------------------------------------------------------------------
// Kernel 2: pairwise MLP + fused softmax + coords. One (b,m) per block,
// grid 512 (= 2 blocks/CU), 512 thr = 8 waves, 8 chunks of 128 n-rows.
// Double-buffered XOR-swizzled LDS staging, ONE barrier per chunk (dbuf
// ordering proof: a wave passes barrier(ch+1) only after its compute(ch)
// LDS reads completed, so writes for ch+2 into the same buffer are safe).
// z kept in LDS; block-local softmax + coords einsum at the end.
// XCD swizzle maps all 64 blocks of a batch onto one XCD (v_h slice
// = 256 KB -> L2-resident).
// -------------------------------------------------------------------------
__global__ __launch_bounds__(512) void pair_attn_fused(
    const f16* __restrict__ v_h, const f16* __restrict__ l_h,
    const float* __restrict__ vc, const float* __restrict__ W2,
    const float* __restrict__ b2, const float* __restrict__ W3,
    float* __restrict__ out_coords, float* __restrict__ out_attn)
{
    __shared__ f16   Xs[2][128 * 128];   // 64 KB double buffer
    __shared__ float zrow[NVN];          // 4 KB
    __shared__ float redm[8], redsum[8];
    __shared__ float redc[3][8];

    const int bid = blockIdx.x;
    const int bm  = (bid & 7) * 64 + (bid >> 3);   // 512 = 8*64, bijective
    const int b   = bm >> 6;

    const int tid  = threadIdx.x;
    const int w    = tid >> 6;          // wave 0..7 -> 16-row stripe
    const int lane = tid & 63;
    const int g    = lane >> 4;
    const int c    = lane & 15;

    // ---- W2 as f16 B-fragments in registers
    f16x8 bw[4][4];
    #pragma unroll
    for (int ks = 0; ks < 4; ++ks)
        #pragma unroll
        for (int fj = 0; fj < 4; ++fj) {
            f16x8 f;
            #pragma unroll
            for (int e = 0; e < 8; ++e)
                f[e] = (f16)W2[(ks * 32 + g * 8 + e) * J + fj * 16 + c];
            bw[ks][fj] = f;
        }

    // ---- l_part fragments (f16, loop-invariant; same m for all waves)
    f16x8 lp[4];
    #pragma unroll
    for (int ks = 0; ks < 4; ++ks)
        lp[ks] = *(const f16x8*)&l_h[(size_t)bm * H + ks * 32 + g * 8];

    float b2r[4], w3r[4];
    #pragma unroll
    for (int fj = 0; fj < 4; ++fj) {
        b2r[fj] = b2[fj * 16 + c];
        w3r[fj] = W3[fj * 16 + c];
    }

    const f16* vsrc = v_h + (size_t)b * NVN * H;

    // staging: 128 rows x 128 f16 = 16384 f16 per chunk; 4 f16x8 per thread.
    // XOR swizzle: 16B-chunk index ^= (row & 7).
    int wr[4];
    #pragma unroll
    for (int i = 0; i < 4; ++i) {
        int fc  = tid + i * 512;
        int row = fc >> 4;
        int ck  = (fc & 15) ^ (row & 7);
        wr[i] = row * 128 + ck * 8;
    }
    const int rrow = (w * 16 + c) * 128;
    const int rx   = c & 7;

    f16x8 st[4];
    #pragma unroll
    for (int i = 0; i < 4; ++i)
        st[i] = *(const f16x8*)&vsrc[(size_t)(tid + i * 512) * 8];

    #pragma unroll 1
    for (int ch = 0; ch < 8; ++ch) {
        f16* buf = Xs[ch & 1];
        #pragma unroll
        for (int i = 0; i < 4; ++i) *(f16x8*)&buf[wr[i]] = st[i];
        __syncthreads();

        if (ch < 7) {                      // issue next chunk's loads early
            const f16* p = vsrc + (size_t)(ch + 1) * 128 * H;
            #pragma unroll
            for (int i = 0; i < 4; ++i)
                st[i] = *(const f16x8*)&p[(size_t)(tid + i * 512) * 8];
        }

        f32x4 acc[4];
        #pragma unroll
        for (int fj = 0; fj < 4; ++fj) acc[fj] = (f32x4){0.f, 0.f, 0.f, 0.f};

        #pragma unroll
        for (int ks = 0; ks < 4; ++ks) {
            f16x8 xv = *(const f16x8*)&buf[rrow + (((ks * 4 + g) ^ rx) * 8)];
            f16x8 af = relu8(xv + lp[ks]);
            #pragma unroll
            for (int fj = 0; fj < 4; ++fj)
                acc[fj] = __builtin_amdgcn_mfma_f32_16x16x32_f16(
                    af, bw[ks][fj], acc[fj], 0, 0, 0);
        }

        // layer 3: z[n] = sum_j relu(acc + b2[j]) * W3[j]; DPP 16-lane reduce
        float pz[4];
        #pragma unroll
        for (int r = 0; r < 4; ++r) {
            float s = fmaxf(acc[0][r] + b2r[0], 0.f) * w3r[0]
                    + fmaxf(acc[1][r] + b2r[1], 0.f) * w3r[1]
                    + fmaxf(acc[2][r] + b2r[2], 0.f) * w3r[2]
                    + fmaxf(acc[3][r] + b2r[3], 0.f) * w3r[3];
            pz[r] = row16_sum(s);
        }
        if (c < 4) {
            float zv = (c == 0) ? pz[0] : (c == 1) ? pz[1] : (c == 2) ? pz[2] : pz[3];
            zrow[ch * 128 + w * 16 + g * 4 + c] = zv;
        }
        // single barrier per chunk (next iteration's __syncthreads)
    }
    __syncthreads();   // zrow complete

    // ---- softmax over 1024 (b3 cancels), 2 elements per thread
    float z0 = zrow[tid], z1 = zrow[tid + 512];
    float mx = fmaxf(z0, z1);
    #pragma unroll
    for (int off = 32; off > 0; off >>= 1) mx = fmaxf(mx, __shfl_xor(mx, off));
    if (lane == 0) redm[w] = mx;
    __syncthreads();
    if (tid == 0) {
        float m = redm[0];
        #pragma unroll
        for (int i = 1; i < 8; ++i) m = fmaxf(m, redm[i]);
        redm[0] = m;
    }
    __syncthreads();
    const float gmax = redm[0];

    z0 = expf(z0 - gmax);
    z1 = expf(z1 - gmax);
    float s = z0 + z1;
    #pragma unroll
    for (int off = 32; off > 0; off >>= 1) s += __shfl_xor(s, off);
    if (lane == 0) redsum[w] = s;
    __syncthreads();
    if (tid == 0) {
        float t = redsum[0];
        #pragma unroll
        for (int i = 1; i < 8; ++i) t += redsum[i];
        redsum[0] = t;
    }
    __syncthreads();
    const float inv = 1.f / redsum[0];

    // ---- attn write + coords accumulate
    float a0 = z0 * inv, a1 = z1 * inv;
    out_attn[(size_t)bm * NVN + tid]       = a0;
    out_attn[(size_t)bm * NVN + tid + 512] = a1;

    const float* v0 = vc + (size_t)(b * NVN + tid) * 3;
    const float* v1 = vc + (size_t)(b * NVN + tid + 512) * 3;
    float cx = a0 * v0[0] + a1 * v1[0];
    float cy = a0 * v0[1] + a1 * v1[1];
    float cz = a0 * v0[2] + a1 * v1[2];
    #pragma unroll
    for (int off = 32; off > 0; off >>= 1) {
        cx += __shfl_xor(cx, off);
        cy += __shfl_xor(cy, off);
        cz += __shfl_xor(cz, off);
    }
    if (lane == 0) { redc[0][w] = cx; redc[1][w] = cy; redc[2][w] = cz; }
    __syncthreads();
    if (tid == 0) {
        float ox = 0.f, oy = 0.f, oz = 0.f;
        #pragma unroll
        for (int i = 0; i < 8; ++i) { ox += redc[0][i]; oy += redc[1][i]; oz += redc[2][i]; }
        out_coords[bm * 3 + 0] = ox;
        out_coords[bm * 3 + 1] = oy;
        out_coords[bm * 3 + 2] = oz;
    }
}

// -------------------------------------------------------------------------
extern "C" void kernel_launch(void* const* d_in, const int* in_sizes, int n_in,
                              void* d_out, int out_size, void* d_ws, size_t ws_size,
                              hipStream_t stream)
{
    const float* VE = (const float*)d_in[0];   // [8192, 128]
    const float* vc = (const float*)d_in[1];   // [8192, 3]
    const float* LE = (const float*)d_in[2];   // [512, 128]
    const float* Wv = (const float*)d_in[6];
    const float* bv = (const float*)d_in[7];
    const float* Wl = (const float*)d_in[8];
    const float* bl = (const float*)d_in[9];
    const float* W1 = (const float*)d_in[10];
    const float* b1 = (const float*)d_in[11];
    const float* W2 = (const float*)d_in[12];
    const float* b2 = (const float*)d_in[13];
    const float* W3 = (const float*)d_in[14];
    // b3 cancels in softmax

    float* ws   = (float*)d_ws;
    f16*   v_hp = (f16*)ws;                        // 8192*128 f16
    f16*   l_hp = v_hp + (size_t)NB * NVN * H;     // 512*128 f16

    float* out_coords = (float*)d_out;             // [512, 3]
    float* out_attn   = out_coords + NB * MLIG * 3;

    project_direct<<<544, 256, 0, stream>>>(
        VE, LE, Wv, bv, Wl, bl, W1, b1, v_hp, l_hp);

    pair_attn_fused<<<512, 512, 0, stream>>>(
        v_hp, l_hp, vc, W2, b2, W3, out_coords, out_attn);
}

// Round 10
// 52.786 us; speedup vs baseline: 8.1350x; 1.0201x over previous
//
#include <hip/hip_runtime.h>
#include <hip/hip_bf16.h>
#include <math.h>

#define H 128
#define NB 8
#define NVN 1024   // virtual nodes per batch
#define MLIG 64    // ligand atoms per batch
#define J 64       // H/2

typedef _Float16 f16;
typedef __attribute__((ext_vector_type(8))) _Float16 f16x8;
typedef __attribute__((ext_vector_type(4))) _Float16 f16x4;
typedef __attribute__((ext_vector_type(4))) float f32x4;

__device__ __forceinline__ f16x8 relu8(f16x8 x) {
    f16x8 z;
    #pragma unroll
    for (int i = 0; i < 8; ++i) z[i] = x[i] > (_Float16)0 ? x[i] : (_Float16)0;
    return z;
}

template <int CTRL>
__device__ __forceinline__ float dpp_add(float x) {
    union { float f; int i; } u, r;
    u.f = x;
    r.i = __builtin_amdgcn_update_dpp(0, u.i, CTRL, 0xf, 0xf, true);
    return x + r.f;
}
__device__ __forceinline__ float row16_sum(float x) {
    x = dpp_add<0xB1>(x);   // xor 1
    x = dpp_add<0x4E>(x);   // xor 2
    x = dpp_add<0x141>(x);  // xor 4 (row_half_mirror)
    x = dpp_add<0x140>(x);  // xor 8 (row_mirror)
    return x;
}

// -------------------------------------------------------------------------
// Kernel 1: direct projection (no combine): v = (VE@Wv+bv)@W1v,
// l = (LE@Wl+bl)@W1l + b1. 16-row tiles, grid 544, f16 out. (R9, passed.)
// -------------------------------------------------------------------------
__global__ __launch_bounds__(256) void project_direct(
    const float* __restrict__ VE, const float* __restrict__ LE,
    const float* __restrict__ Wv, const float* __restrict__ bv,
    const float* __restrict__ Wl, const float* __restrict__ bl,
    const float* __restrict__ W1, const float* __restrict__ b1,
    f16* __restrict__ v_h, f16* __restrict__ l_h)
{
    __shared__ float Xs[16][132];
    __shared__ float Ts[16][132];
    const int bid = blockIdx.x;
    const int tid = threadIdx.x;

    const float* src; const float* Wa; const float* ba; const float* Wb;
    f16* dst; int r0; bool lig;
    if (bid < 512) { src = VE; Wa = Wv; ba = bv; Wb = W1 + H * H;
                     dst = v_h; r0 = bid * 16; lig = false; }
    else           { src = LE; Wa = Wl; ba = bl; Wb = W1;
                     dst = l_h; r0 = (bid - 512) * 16; lig = true; }

    #pragma unroll
    for (int i = 0; i < 2; ++i) {
        int s = tid + i * 256;
        int r = s >> 5, c4 = (s & 31) * 4;
        *(f32x4*)&Xs[r][c4] = *(const f32x4*)&src[(size_t)(r0 + r) * H + c4];
    }
    __syncthreads();

    const int rt = (tid >> 5) * 2;
    const int c0 = (tid & 31) * 4;

    f32x4 a0 = *(const f32x4*)&ba[c0];
    f32x4 a1 = a0;
    #pragma unroll 4
    for (int k4 = 0; k4 < 32; ++k4) {
        f32x4 x0 = *(const f32x4*)&Xs[rt][k4 * 4];
        f32x4 x1 = *(const f32x4*)&Xs[rt + 1][k4 * 4];
        f32x4 w0 = *(const f32x4*)&Wa[(size_t)(k4 * 4 + 0) * H + c0];
        f32x4 w1 = *(const f32x4*)&Wa[(size_t)(k4 * 4 + 1) * H + c0];
        f32x4 w2 = *(const f32x4*)&Wa[(size_t)(k4 * 4 + 2) * H + c0];
        f32x4 w3 = *(const f32x4*)&Wa[(size_t)(k4 * 4 + 3) * H + c0];
        a0 += x0[0] * w0; a0 += x0[1] * w1; a0 += x0[2] * w2; a0 += x0[3] * w3;
        a1 += x1[0] * w0; a1 += x1[1] * w1; a1 += x1[2] * w2; a1 += x1[3] * w3;
    }
    *(f32x4*)&Ts[rt][c0]     = a0;
    *(f32x4*)&Ts[rt + 1][c0] = a1;
    __syncthreads();

    f32x4 b0;
    if (lig) b0 = *(const f32x4*)&b1[c0];
    else     b0 = (f32x4){0.f, 0.f, 0.f, 0.f};
    f32x4 b1a = b0;
    #pragma unroll 4
    for (int k4 = 0; k4 < 32; ++k4) {
        f32x4 x0 = *(const f32x4*)&Ts[rt][k4 * 4];
        f32x4 x1 = *(const f32x4*)&Ts[rt + 1][k4 * 4];
        f32x4 w0 = *(const f32x4*)&Wb[(size_t)(k4 * 4 + 0) * H + c0];
        f32x4 w1 = *(const f32x4*)&Wb[(size_t)(k4 * 4 + 1) * H + c0];
        f32x4 w2 = *(const f32x4*)&Wb[(size_t)(k4 * 4 + 2) * H + c0];
        f32x4 w3 = *(const f32x4*)&Wb[(size_t)(k4 * 4 + 3) * H + c0];
        b0  += x0[0] * w0; b0  += x0[1] * w1; b0  += x0[2] * w2; b0  += x0[3] * w3;
        b1a += x1[0] * w0; b1a += x1[1] * w1; b1a += x1[2] * w2; b1a += x1[3] * w3;
    }

    f16x4 h0, h1;
    #pragma unroll
    for (int i = 0; i < 4; ++i) { h0[i] = (f16)b0[i]; h1[i] = (f16)b1a[i]; }
    *(f16x4*)&dst[(size_t)(r0 + rt) * H + c0]     = h0;
    *(f16x4*)&dst[(size_t)(r0 + rt + 1) * H + c0] = h1;
}

// -------------------------------------------------------------------------
// Kernel 2: pairwise MLP -> z. Grid 1024 = (bm, n-half), 256 thr = 4 waves,
// 4 blocks/CU (LDS 32.8 KB, 16 waves/CU). 8 chunks of 64 n-rows,
// double-buffered XOR-swizzled staging, ONE barrier per chunk, DPP layer-3
// reduce, z -> global. XCD swizzle: each XCD owns one batch (256 KB v_h
// slice L2-resident).
// -------------------------------------------------------------------------
__global__ __launch_bounds__(256) void pair_z(
    const f16* __restrict__ v_h, const f16* __restrict__ l_h,
    const float* __restrict__ W2, const float* __restrict__ b2,
    const float* __restrict__ W3, float* __restrict__ zbuf)
{
    __shared__ f16 Xs[2][64 * 128];    // 32 KB double buffer

    const int bid = blockIdx.x;
    // 128 blocks per batch; xcd = bid&7 owns batch xcd.
    const int xcd = bid & 7;
    const int i   = bid >> 3;          // 0..127 within batch
    const int bm  = xcd * 64 + (i >> 1);
    const int half = i & 1;
    const int b   = bm >> 6;

    const int tid  = threadIdx.x;
    const int w    = tid >> 6;         // wave 0..3 -> 16-row stripe
    const int lane = tid & 63;
    const int g    = lane >> 4;
    const int c    = lane & 15;

    // W2 as f16 B-fragments in registers
    f16x8 bw[4][4];
    #pragma unroll
    for (int ks = 0; ks < 4; ++ks)
        #pragma unroll
        for (int fj = 0; fj < 4; ++fj) {
            f16x8 f;
            #pragma unroll
            for (int e = 0; e < 8; ++e)
                f[e] = (f16)W2[(ks * 32 + g * 8 + e) * J + fj * 16 + c];
            bw[ks][fj] = f;
        }

    f16x8 lp[4];
    #pragma unroll
    for (int ks = 0; ks < 4; ++ks)
        lp[ks] = *(const f16x8*)&l_h[(size_t)bm * H + ks * 32 + g * 8];

    float b2r[4], w3r[4];
    #pragma unroll
    for (int fj = 0; fj < 4; ++fj) {
        b2r[fj] = b2[fj * 16 + c];
        w3r[fj] = W3[fj * 16 + c];
    }

    const f16* vsrc = v_h + ((size_t)b * NVN + half * 512) * H;

    // staging: 64 rows x 128 f16 per chunk; 4 f16x8 per thread.
    int wr[4];
    #pragma unroll
    for (int i2 = 0; i2 < 4; ++i2) {
        int fc  = tid + i2 * 256;
        int row = fc >> 4;
        int ck  = (fc & 15) ^ (row & 7);
        wr[i2] = row * 128 + ck * 8;
    }
    const int rrow = (w * 16 + c) * 128;
    const int rx   = c & 7;

    f16x8 st[4];
    #pragma unroll
    for (int i2 = 0; i2 < 4; ++i2)
        st[i2] = *(const f16x8*)&vsrc[(size_t)(tid + i2 * 256) * 8];

    float* zdst = zbuf + (size_t)bm * NVN + half * 512;

    #pragma unroll 1
    for (int ch = 0; ch < 8; ++ch) {
        f16* buf = Xs[ch & 1];
        #pragma unroll
        for (int i2 = 0; i2 < 4; ++i2) *(f16x8*)&buf[wr[i2]] = st[i2];
        __syncthreads();

        if (ch < 7) {                  // issue next chunk's loads early
            const f16* p = vsrc + (size_t)(ch + 1) * 64 * H;
            #pragma unroll
            for (int i2 = 0; i2 < 4; ++i2)
                st[i2] = *(const f16x8*)&p[(size_t)(tid + i2 * 256) * 8];
        }

        f32x4 acc[4];
        #pragma unroll
        for (int fj = 0; fj < 4; ++fj) acc[fj] = (f32x4){0.f, 0.f, 0.f, 0.f};

        #pragma unroll
        for (int ks = 0; ks < 4; ++ks) {
            f16x8 xv = *(const f16x8*)&buf[rrow + (((ks * 4 + g) ^ rx) * 8)];
            f16x8 af = relu8(xv + lp[ks]);
            #pragma unroll
            for (int fj = 0; fj < 4; ++fj)
                acc[fj] = __builtin_amdgcn_mfma_f32_16x16x32_f16(
                    af, bw[ks][fj], acc[fj], 0, 0, 0);
        }

        float pz[4];
        #pragma unroll
        for (int r = 0; r < 4; ++r) {
            float s = fmaxf(acc[0][r] + b2r[0], 0.f) * w3r[0]
                    + fmaxf(acc[1][r] + b2r[1], 0.f) * w3r[1]
                    + fmaxf(acc[2][r] + b2r[2], 0.f) * w3r[2]
                    + fmaxf(acc[3][r] + b2r[3], 0.f) * w3r[3];
            pz[r] = row16_sum(s);
        }
        if (c < 4) {
            float zv = (c == 0) ? pz[0] : (c == 1) ? pz[1] : (c == 2) ? pz[2] : pz[3];
            zdst[ch * 64 + w * 16 + g * 4 + c] = zv;
        }
        // single barrier per chunk (next iteration's __syncthreads orders
        // write(ch+2) after all compute(ch) reads via the dbuf argument).
    }
}

// -------------------------------------------------------------------------
// Kernel 3: per-(b,m) softmax over z + attn write + coords einsum. (R6, 1.2us)
// -------------------------------------------------------------------------
__global__ __launch_bounds__(256) void softmax_coords(
    const float* __restrict__ zbuf, const float* __restrict__ vc,
    float* __restrict__ out_coords, float* __restrict__ out_attn)
{
    __shared__ float red[4];
    __shared__ float redc[3][4];

    const int tid = threadIdx.x;
    const int bm  = blockIdx.x;
    const int b   = bm >> 6;
    const int wid = tid >> 6, lane = tid & 63;

    float zloc[4];
    float mx = -INFINITY;
    #pragma unroll
    for (int k = 0; k < 4; ++k) {
        zloc[k] = zbuf[(size_t)bm * NVN + tid + k * 256];
        mx = fmaxf(mx, zloc[k]);
    }
    #pragma unroll
    for (int off = 32; off > 0; off >>= 1) mx = fmaxf(mx, __shfl_xor(mx, off));
    if (lane == 0) red[wid] = mx;
    __syncthreads();
    if (tid == 0)
        red[0] = fmaxf(fmaxf(red[0], red[1]), fmaxf(red[2], red[3]));
    __syncthreads();
    const float gmax = red[0];
    __syncthreads();

    float s = 0.f;
    #pragma unroll
    for (int k = 0; k < 4; ++k) {
        zloc[k] = expf(zloc[k] - gmax);
        s += zloc[k];
    }
    #pragma unroll
    for (int off = 32; off > 0; off >>= 1) s += __shfl_xor(s, off);
    if (lane == 0) red[wid] = s;
    __syncthreads();
    if (tid == 0) red[0] = red[0] + red[1] + red[2] + red[3];
    __syncthreads();
    const float inv = 1.f / red[0];

    float cx = 0.f, cy = 0.f, cz = 0.f;
    #pragma unroll
    for (int k = 0; k < 4; ++k) {
        int n = tid + k * 256;
        float a = zloc[k] * inv;
        out_attn[(size_t)bm * NVN + n] = a;
        const float* vcp = vc + (size_t)(b * NVN + n) * 3;
        cx += a * vcp[0];
        cy += a * vcp[1];
        cz += a * vcp[2];
    }
    #pragma unroll
    for (int off = 32; off > 0; off >>= 1) {
        cx += __shfl_xor(cx, off);
        cy += __shfl_xor(cy, off);
        cz += __shfl_xor(cz, off);
    }
    if (lane == 0) { redc[0][wid] = cx; redc[1][wid] = cy; redc[2][wid] = cz; }
    __syncthreads();
    if (tid == 0) {
        out_coords[bm * 3 + 0] = redc[0][0] + redc[0][1] + redc[0][2] + redc[0][3];
        out_coords[bm * 3 + 1] = redc[1][0] + redc[1][1] + redc[1][2] + redc[1][3];
        out_coords[bm * 3 + 2] = redc[2][0] + redc[2][1] + redc[2][2] + redc[2][3];
    }
}

// -------------------------------------------------------------------------
extern "C" void kernel_launch(void* const* d_in, const int* in_sizes, int n_in,
                              void* d_out, int out_size, void* d_ws, size_t ws_size,
                              hipStream_t stream)
{
    const float* VE = (const float*)d_in[0];   // [8192, 128]
    const float* vc = (const float*)d_in[1];   // [8192, 3]
    const float* LE = (const float*)d_in[2];   // [512, 128]
    const float* Wv = (const float*)d_in[6];
    const float* bv = (const float*)d_in[7];
    const float* Wl = (const float*)d_in[8];
    const float* bl = (const float*)d_in[9];
    const float* W1 = (const float*)d_in[10];
    const float* b1 = (const float*)d_in[11];
    const float* W2 = (const float*)d_in[12];
    const float* b2 = (const float*)d_in[13];
    const float* W3 = (const float*)d_in[14];
    // b3 cancels in softmax

    float* ws   = (float*)d_ws;
    f16*   v_hp = (f16*)ws;                        // 8192*128 f16 = 2 MB
    f16*   l_hp = v_hp + (size_t)NB * NVN * H;     // 512*128 f16
    float* zbuf = (float*)(l_hp + (size_t)NB * MLIG * H);  // 512*1024 fp32

    float* out_coords = (float*)d_out;             // [512, 3]
    float* out_attn   = out_coords + NB * MLIG * 3;

    project_direct<<<544, 256, 0, stream>>>(
        VE, LE, Wv, bv, Wl, bl, W1, b1, v_hp, l_hp);

    pair_z<<<1024, 256, 0, stream>>>(
        v_hp, l_hp, W2, b2, W3, zbuf);

    softmax_coords<<<NB * MLIG, 256, 0, stream>>>(
        zbuf, vc, out_coords, out_attn);
}